// Round 4
// baseline (925.113 us; speedup 1.0000x reference)
//
#include <hip/hip_runtime.h>
#include <hip/hip_bf16.h>
#include <math.h>

#define HF 128
#define NL 128
#define NP 1024
#define NB 4
#define EPSF 1e-8f

typedef short bf16x8 __attribute__((ext_vector_type(8)));
typedef float f32x4 __attribute__((ext_vector_type(4)));

__device__ __forceinline__ float fast_rcp(float x){ return __builtin_amdgcn_rcpf(x); }
__device__ __forceinline__ float silu_f(float x){ return x*fast_rcp(1.f+__expf(-x)); }
__device__ __forceinline__ float sigmoid_f(float x){ return fast_rcp(1.f+__expf(-x)); }
__device__ __forceinline__ float tanh_f(float x){ return 1.f - 2.f*fast_rcp(1.f+__expf(2.f*x)); }
__device__ __forceinline__ unsigned short f2bf(float f){ __hip_bfloat16 h=__float2bfloat16(f); return *(unsigned short*)&h; }
__device__ __forceinline__ float bf2f(short u){ unsigned int x = ((unsigned int)(unsigned short)u)<<16; float r; __builtin_memcpy(&r,&x,4); return r; }

// ---------------------------------------------------------------------------
// Precompute:
//   Al = hl@aW1[0:128]+ab1 (f32), Cl = hl@cW1[0:128]+cb1 (f32)
//   Ap = hp@aW1[128:256] (bf16), Vp = hp@vW1[0:128]+vb1 (bf16), Cp = hp@cW1[128:256] (bf16)
//   WaT/WvT = aW2^T / vW2^T as bf16 [n][k]
// ---------------------------------------------------------------------------
__global__ __launch_bounds__(128) void precompute_kernel(
    const float* __restrict__ h_ligand, const float* __restrict__ h_protein,
    const float* __restrict__ aW1, const float* __restrict__ ab1,
    const float* __restrict__ vW1, const float* __restrict__ vb1,
    const float* __restrict__ cW1, const float* __restrict__ cb1,
    const float* __restrict__ aW2, const float* __restrict__ vW2,
    float* __restrict__ Al, float* __restrict__ Cl,
    unsigned short* __restrict__ Ap, unsigned short* __restrict__ Vp,
    unsigned short* __restrict__ Cp,
    unsigned short* __restrict__ WaT, unsigned short* __restrict__ WvT)
{
    const int blk = blockIdx.x, n = threadIdx.x;
    if (blk < 64) {
        __shared__ float rows[8][HF];
        const int r0 = blk*8;
        for (int idx=n; idx<8*HF; idx+=128) rows[idx>>7][idx&127] = h_ligand[r0*HF+idx];
        __syncthreads();
        float aA[8], aC[8];
        const float bA = ab1[n], bC = cb1[n];
        #pragma unroll
        for (int r=0;r<8;++r){ aA[r]=bA; aC[r]=bC; }
        #pragma unroll 4
        for (int k=0;k<HF;++k){
            float wA = aW1[k*HF+n], wC = cW1[k*HF+n];
            #pragma unroll
            for (int r=0;r<8;++r){ aA[r]=fmaf(rows[r][k],wA,aA[r]); aC[r]=fmaf(rows[r][k],wC,aC[r]); }
        }
        #pragma unroll
        for (int r=0;r<8;++r){ Al[(r0+r)*HF+n]=aA[r]; Cl[(r0+r)*HF+n]=aC[r]; }
    } else if (blk < 576) {
        __shared__ float rows[8][HF];
        const int r0 = (blk-64)*8;
        for (int idx=n; idx<8*HF; idx+=128) rows[idx>>7][idx&127] = h_protein[r0*HF+idx];
        __syncthreads();
        float aA[8], aV[8], aC[8];
        const float bV = vb1[n];
        #pragma unroll
        for (int r=0;r<8;++r){ aA[r]=0.f; aV[r]=bV; aC[r]=0.f; }
        #pragma unroll 2
        for (int k=0;k<HF;++k){
            float wA = aW1[(HF+k)*HF+n], wV = vW1[k*HF+n], wC = cW1[(HF+k)*HF+n];
            #pragma unroll
            for (int r=0;r<8;++r){
                float h = rows[r][k];
                aA[r]=fmaf(h,wA,aA[r]); aV[r]=fmaf(h,wV,aV[r]); aC[r]=fmaf(h,wC,aC[r]);
            }
        }
        #pragma unroll
        for (int r=0;r<8;++r){
            Ap[(r0+r)*HF+n]=f2bf(aA[r]); Vp[(r0+r)*HF+n]=f2bf(aV[r]); Cp[(r0+r)*HF+n]=f2bf(aC[r]);
        }
    } else {
        const int m = blk - 576;         // 0..15: 8 blocks aW2, 8 blocks vW2
        const float* W = (m<8) ? aW2 : vW2;
        unsigned short* WT = (m<8) ? WaT : WvT;
        const int n0 = (m&7)*16;
        #pragma unroll
        for (int kb=0; kb<16; ++kb) {
            int k = kb*8 + (n>>4);
            int col = n0 + (n&15);
            WT[col*HF + k] = f2bf(W[k*HF + col]);
        }
    }
}

// ---------------------------------------------------------------------------
// Main fused kernel: grid = 1024 blocks = (b,i,jhalf); 256 threads = 4 waves.
// Edge-compaction of the 512-j range, then barrier-free main loop:
// each wave owns 16 rows x full n=128; A/V fragments built in registers,
// weight B-fragments streamed from L2 (bf16 W^T).  attn reduced via shfl.
// ---------------------------------------------------------------------------
__global__ __launch_bounds__(256,4) void egnn_main_kernel(
    const float* __restrict__ x_ligand, const float* __restrict__ x_protein,
    const float* __restrict__ ligand_mask, const float* __restrict__ protein_mask,
    const float* __restrict__ aW1, const float* __restrict__ ab2,
    const float* __restrict__ aW3, const float* __restrict__ ab3,
    const float* __restrict__ vW1, const float* __restrict__ vb2,
    const float* __restrict__ cW1, const float* __restrict__ cW2, const float* __restrict__ cb2,
    const float* __restrict__ Al, const float* __restrict__ Cl,
    const unsigned short* __restrict__ Ap, const unsigned short* __restrict__ Vp,
    const unsigned short* __restrict__ Cp,
    const unsigned short* __restrict__ WaT, const unsigned short* __restrict__ WvT,
    float* __restrict__ out)
{
    __shared__ float ds_all[512], pme[512], dirx[512], diry[512], dirz[512];
    __shared__ unsigned short jlist[512];
    __shared__ float Al_s[HF], aw1l[HF], vw1l[HF];
    __shared__ float Cl_s[HF], cw1l[HF], cW2s[HF];
    __shared__ float2 aa3[HF];          // {ab2, aW3}
    __shared__ float vb2s[HF];
    __shared__ float hred[4][HF];
    __shared__ float xw[4][3];
    __shared__ int nact_s;

    const int t = threadIdx.x, lane = t&63, w = t>>6;
    const int lr = lane&15, lg = lane>>4;
    const int bi = blockIdx.x;
    const int half = bi & 1;
    const int ii = bi >> 1;              // b*128 + i
    const int b = ii >> 7;
    const int jbase = half*512;

    // ---- prologue: constants ----
    if (t < HF) {
        Al_s[t] = Al[(size_t)ii*HF+t];
        Cl_s[t] = Cl[(size_t)ii*HF+t];
        aw1l[t] = aW1[256*HF+t];
        cw1l[t] = cW1[256*HF+t];
        vw1l[t] = vW1[128*HF+t];
        cW2s[t] = cW2[t];
        vb2s[t] = vb2[t];
        aa3[t]  = make_float2(ab2[t], aW3[t]);
    }
    // ---- prologue: geometry for 512 j ----
    const float xl0 = x_ligand[ii*3+0], xl1 = x_ligand[ii*3+1], xl2 = x_ligand[ii*3+2];
    const float* xp = x_protein + ((size_t)b*NP + jbase)*3;
    const float* pm = protein_mask + (size_t)b*NP + jbase;
    #pragma unroll
    for (int q=0; q<2; ++q) {
        int jj = q*256 + t;
        float r0 = xl0-xp[jj*3+0], r1 = xl1-xp[jj*3+1], r2 = xl2-xp[jj*3+2];
        float ds = r0*r0+r1*r1+r2*r2;
        float dist = sqrtf(ds+EPSF);
        float inv = fast_rcp(dist+EPSF);
        float e = dist < 10.f ? 1.f : 0.f;
        ds_all[jj]=ds; pme[jj]=pm[jj]*e;
        dirx[jj]=r0*inv; diry[jj]=r1*inv; dirz[jj]=r2*inv;
    }
    __syncthreads();
    // ---- compaction (wave 0) ----
    if (w == 0) {
        int base = 0;
        for (int c=0; c<8; ++c) {
            int jj = c*64 + lane;
            bool act = pme[jj] > 0.f;
            unsigned long long m = __ballot(act);
            int pos = base + __popcll(m & ((1ull<<lane)-1ull));
            if (act) jlist[pos] = (unsigned short)jj;
            base += __popcll(m);
        }
        if (lane == 0) nact_s = base;
    }
    __syncthreads();
    const int nact = nact_s;
    const int ntiles = (nact + 63) >> 6;

    const unsigned short* Ap_b = Ap + ((size_t)b*NP + jbase)*HF;
    const unsigned short* Vp_b = Vp + ((size_t)b*NP + jbase)*HF;
    const unsigned short* Cp_b = Cp + ((size_t)b*NP + jbase)*HF;
    const float ab3v = ab3[0], cb2v = cb2[0];

    float hacc[8] = {0.f,0.f,0.f,0.f,0.f,0.f,0.f,0.f};
    float sae = 0.f;
    float xa0 = 0.f, xa1 = 0.f, xa2 = 0.f;
    const int crow = t >> 2, cg = t & 3;   // c-branch: row 0..63, group 0..3 (32 ch)

    for (int tile = 0; tile < ntiles; ++tile) {
        const int j0 = tile*64;

        // ---- A-fragments in registers: rows w*16+lr, k-chunk lg ----
        const int grow = j0 + w*16 + lr;
        const bool ok = grow < nact;
        const int jl = jlist[ok ? grow : 0];
        const float dsv = ds_all[jl];
        bf16x8 af[4];
        #pragma unroll
        for (int ks=0; ks<4; ++ks) {
            const int ch = ks*32 + lg*8;
            bf16x8 ap = *(const bf16x8*)(Ap_b + (size_t)jl*HF + ch);
            f32x4 al0 = *(const f32x4*)&Al_s[ch];
            f32x4 al1 = *(const f32x4*)&Al_s[ch+4];
            f32x4 w0  = *(const f32x4*)&aw1l[ch];
            f32x4 w1  = *(const f32x4*)&aw1l[ch+4];
            bf16x8 o;
            #pragma unroll
            for (int q=0;q<4;++q) {
                o[q]   = (short)f2bf(silu_f(al0[q] + bf2f(ap[q])   + dsv*w0[q]));
                o[q+4] = (short)f2bf(silu_f(al1[q] + bf2f(ap[q+4]) + dsv*w1[q]));
            }
            af[ks] = o;
        }
        // ---- a-GEMM: stream aW2^T B-frags from L2 ----
        f32x4 acc[8];
        #pragma unroll
        for (int nt=0; nt<8; ++nt) {
            const unsigned short* wp = WaT + (size_t)(nt*16+lr)*HF + lg*8;
            f32x4 a = {0.f,0.f,0.f,0.f};
            #pragma unroll
            for (int ks=0; ks<4; ++ks) {
                bf16x8 wb = *(const bf16x8*)(wp + ks*32);
                a = __builtin_amdgcn_mfma_f32_16x16x32_bf16(af[ks], wb, a, 0,0,0);
            }
            acc[nt] = a;
        }
        // ---- attn epilogue (all in-wave) ----
        float ae[4];
        #pragma unroll
        for (int r=0; r<4; ++r) {
            float p = 0.f;
            #pragma unroll
            for (int nt=0; nt<8; ++nt) {
                float2 c2 = aa3[nt*16+lr];
                p += silu_f(acc[nt][r] + c2.x) * c2.y;
            }
            p += __shfl_xor(p,1); p += __shfl_xor(p,2);
            p += __shfl_xor(p,4); p += __shfl_xor(p,8);
            const int growr = j0 + w*16 + lg*4 + r;
            const bool okr = growr < nact;
            const int jlr = jlist[okr ? growr : 0];
            const float pmer = okr ? pme[jlr] : 0.f;
            ae[r] = sigmoid_f(p + ab3v) * pmer;
            sae += ae[r];
        }
        // ---- V-fragments + v-GEMM, fold into hacc ----
        bf16x8 vf[4];
        #pragma unroll
        for (int ks=0; ks<4; ++ks) {
            const int ch = ks*32 + lg*8;
            bf16x8 vp = *(const bf16x8*)(Vp_b + (size_t)jl*HF + ch);
            f32x4 w0 = *(const f32x4*)&vw1l[ch];
            f32x4 w1 = *(const f32x4*)&vw1l[ch+4];
            bf16x8 o;
            #pragma unroll
            for (int q=0;q<4;++q) {
                o[q]   = (short)f2bf(silu_f(bf2f(vp[q])   + dsv*w0[q]));
                o[q+4] = (short)f2bf(silu_f(bf2f(vp[q+4]) + dsv*w1[q]));
            }
            vf[ks] = o;
        }
        #pragma unroll
        for (int nt=0; nt<8; ++nt) {
            const unsigned short* wp = WvT + (size_t)(nt*16+lr)*HF + lg*8;
            f32x4 a = {0.f,0.f,0.f,0.f};
            #pragma unroll
            for (int ks=0; ks<4; ++ks) {
                bf16x8 wb = *(const bf16x8*)(wp + ks*32);
                a = __builtin_amdgcn_mfma_f32_16x16x32_bf16(vf[ks], wb, a, 0,0,0);
            }
            hacc[nt] += ae[0]*a[0] + ae[1]*a[1] + ae[2]*a[2] + ae[3]*a[3];
        }
        // ---- c-branch (VALU) ----
        {
            const int growc = j0 + crow;
            const bool okc = growc < nact;
            const int jlc = jlist[okc ? growc : 0];
            const float pmec = okc ? pme[jlc] : 0.f;
            const float dsc = ds_all[jlc];
            float part = 0.f;
            const unsigned short* cp = Cp_b + (size_t)jlc*HF + cg*32;
            #pragma unroll
            for (int u=0; u<4; ++u) {
                const int ch = cg*32 + u*8;
                bf16x8 cv = *(const bf16x8*)(cp + u*8);
                f32x4 cl0 = *(const f32x4*)&Cl_s[ch];
                f32x4 cl1 = *(const f32x4*)&Cl_s[ch+4];
                f32x4 w0  = *(const f32x4*)&cw1l[ch];
                f32x4 w1  = *(const f32x4*)&cw1l[ch+4];
                f32x4 s0  = *(const f32x4*)&cW2s[ch];
                f32x4 s1  = *(const f32x4*)&cW2s[ch+4];
                #pragma unroll
                for (int q=0;q<4;++q) {
                    part += silu_f(cl0[q] + bf2f(cv[q])   + dsc*w0[q]) * s0[q];
                    part += silu_f(cl1[q] + bf2f(cv[q+4]) + dsc*w1[q]) * s1[q];
                }
            }
            part += __shfl_xor(part,1); part += __shfl_xor(part,2);
            if (cg == 0) {
                float cw = tanh_f(part + cb2v) * pmec;
                xa0 = fmaf(dirx[jlc], cw, xa0);
                xa1 = fmaf(diry[jlc], cw, xa1);
                xa2 = fmaf(dirz[jlc], cw, xa2);
            }
        }
    }

    // ---- final reductions ----
    #pragma unroll
    for (int nt=0; nt<8; ++nt) {
        hacc[nt] += __shfl_xor(hacc[nt],16);
        hacc[nt] += __shfl_xor(hacc[nt],32);
    }
    sae += __shfl_xor(sae,16);
    sae += __shfl_xor(sae,32);
    if (lg == 0) {
        #pragma unroll
        for (int nt=0; nt<8; ++nt)
            hred[w][nt*16+lr] = hacc[nt] + vb2s[nt*16+lr]*sae;
    }
    xa0 += __shfl_xor(xa0,1);  xa1 += __shfl_xor(xa1,1);  xa2 += __shfl_xor(xa2,1);
    xa0 += __shfl_xor(xa0,2);  xa1 += __shfl_xor(xa1,2);  xa2 += __shfl_xor(xa2,2);
    xa0 += __shfl_xor(xa0,4);  xa1 += __shfl_xor(xa1,4);  xa2 += __shfl_xor(xa2,4);
    xa0 += __shfl_xor(xa0,8);  xa1 += __shfl_xor(xa1,8);  xa2 += __shfl_xor(xa2,8);
    xa0 += __shfl_xor(xa0,16); xa1 += __shfl_xor(xa1,16); xa2 += __shfl_xor(xa2,16);
    xa0 += __shfl_xor(xa0,32); xa1 += __shfl_xor(xa1,32); xa2 += __shfl_xor(xa2,32);
    if (lane == 0) { xw[w][0]=xa0; xw[w][1]=xa1; xw[w][2]=xa2; }
    __syncthreads();

    const float lm = ligand_mask[ii];
    if (t < HF) {
        float v = (hred[0][t]+hred[1][t]+hred[2][t]+hred[3][t]) * 0.01f * lm;
        atomicAdd(&out[(size_t)ii*HF + t], v);
    }
    if (t < 3) {
        float v = (xw[0][t]+xw[1][t]+xw[2][t]+xw[3][t]) * 0.01f * lm;
        atomicAdd(&out[(size_t)NB*NL*HF + ii*3 + t], v);
    }
}

extern "C" void kernel_launch(void* const* d_in, const int* in_sizes, int n_in,
                              void* d_out, int out_size, void* d_ws, size_t ws_size,
                              hipStream_t stream) {
    const float* h_ligand     = (const float*)d_in[0];
    const float* x_ligand     = (const float*)d_in[1];
    const float* h_protein    = (const float*)d_in[2];
    const float* x_protein    = (const float*)d_in[3];
    const float* ligand_mask  = (const float*)d_in[4];
    const float* protein_mask = (const float*)d_in[5];
    const float* aW1 = (const float*)d_in[6];
    const float* ab1 = (const float*)d_in[7];
    const float* aW2 = (const float*)d_in[8];
    const float* ab2 = (const float*)d_in[9];
    const float* aW3 = (const float*)d_in[10];
    const float* ab3 = (const float*)d_in[11];
    const float* vW1 = (const float*)d_in[12];
    const float* vb1 = (const float*)d_in[13];
    const float* vW2 = (const float*)d_in[14];
    const float* vb2 = (const float*)d_in[15];
    const float* cW1 = (const float*)d_in[16];
    const float* cb1 = (const float*)d_in[17];
    const float* cW2 = (const float*)d_in[18];
    const float* cb2 = (const float*)d_in[19];

    // workspace layout (all chunks 256B-aligned)
    float* Al = (float*)d_ws;                              // 512*128 f32
    float* Cl = Al + 512*HF;                               // 512*128 f32
    unsigned short* Ap  = (unsigned short*)(Cl + 512*HF);  // 4096*128 bf16
    unsigned short* Vp  = Ap + (size_t)NB*NP*HF;
    unsigned short* Cp  = Vp + (size_t)NB*NP*HF;
    unsigned short* WaT = Cp + (size_t)NB*NP*HF;           // 128*128 bf16
    unsigned short* WvT = WaT + HF*HF;

    hipMemsetAsync(d_out, 0, (size_t)out_size*sizeof(float), stream);

    precompute_kernel<<<592, 128, 0, stream>>>(
        h_ligand, h_protein, aW1, ab1, vW1, vb1, cW1, cb1, aW2, vW2,
        Al, Cl, Ap, Vp, Cp, WaT, WvT);

    egnn_main_kernel<<<NB*NL*2, 256, 0, stream>>>(
        x_ligand, x_protein, ligand_mask, protein_mask,
        aW1, ab2, aW3, ab3, vW1, vb2, cW1, cW2, cb2,
        Al, Cl, Ap, Vp, Cp, WaT, WvT, (float*)d_out);
}

// Round 5
// 563.850 us; speedup vs baseline: 1.6407x; 1.6407x over previous
//
#include <hip/hip_runtime.h>
#include <hip/hip_bf16.h>
#include <math.h>

#define HF 128
#define NL 128
#define NP 1024
#define NB 4
#define EPSF 1e-8f

typedef short bf16x8 __attribute__((ext_vector_type(8)));
typedef float f32x4 __attribute__((ext_vector_type(4)));

__device__ __forceinline__ float fast_rcp(float x){ return __builtin_amdgcn_rcpf(x); }
__device__ __forceinline__ float silu_f(float x){ return x*fast_rcp(1.f+__expf(-x)); }
__device__ __forceinline__ float sigmoid_f(float x){ return fast_rcp(1.f+__expf(-x)); }
__device__ __forceinline__ float tanh_f(float x){ return 1.f - 2.f*fast_rcp(1.f+__expf(2.f*x)); }
__device__ __forceinline__ unsigned short f2bf(float f){ __hip_bfloat16 h=__float2bfloat16(f); return *(unsigned short*)&h; }
__device__ __forceinline__ float bf2f(short u){ unsigned int x = ((unsigned int)(unsigned short)u)<<16; float r; __builtin_memcpy(&r,&x,4); return r; }

// ---------------------------------------------------------------------------
// Precompute:
//   Al = hl@aW1[0:128]+ab1 (f32), Cl = hl@cW1[0:128]+cb1 (f32)
//   Ap = hp@aW1[128:256] (bf16), Vp = hp@vW1[0:128]+vb1 (bf16), Cp = hp@cW1[128:256] (bf16)
//   WaT/WvT = aW2^T / vW2^T as bf16 [n][k]
// ---------------------------------------------------------------------------
__global__ __launch_bounds__(128) void precompute_kernel(
    const float* __restrict__ h_ligand, const float* __restrict__ h_protein,
    const float* __restrict__ aW1, const float* __restrict__ ab1,
    const float* __restrict__ vW1, const float* __restrict__ vb1,
    const float* __restrict__ cW1, const float* __restrict__ cb1,
    const float* __restrict__ aW2, const float* __restrict__ vW2,
    float* __restrict__ Al, float* __restrict__ Cl,
    unsigned short* __restrict__ Ap, unsigned short* __restrict__ Vp,
    unsigned short* __restrict__ Cp,
    unsigned short* __restrict__ WaT, unsigned short* __restrict__ WvT)
{
    const int blk = blockIdx.x, n = threadIdx.x;
    if (blk < 64) {
        __shared__ float rows[8][HF];
        const int r0 = blk*8;
        for (int idx=n; idx<8*HF; idx+=128) rows[idx>>7][idx&127] = h_ligand[r0*HF+idx];
        __syncthreads();
        float aA[8], aC[8];
        const float bA = ab1[n], bC = cb1[n];
        #pragma unroll
        for (int r=0;r<8;++r){ aA[r]=bA; aC[r]=bC; }
        #pragma unroll 4
        for (int k=0;k<HF;++k){
            float wA = aW1[k*HF+n], wC = cW1[k*HF+n];
            #pragma unroll
            for (int r=0;r<8;++r){ aA[r]=fmaf(rows[r][k],wA,aA[r]); aC[r]=fmaf(rows[r][k],wC,aC[r]); }
        }
        #pragma unroll
        for (int r=0;r<8;++r){ Al[(r0+r)*HF+n]=aA[r]; Cl[(r0+r)*HF+n]=aC[r]; }
    } else if (blk < 576) {
        __shared__ float rows[8][HF];
        const int r0 = (blk-64)*8;
        for (int idx=n; idx<8*HF; idx+=128) rows[idx>>7][idx&127] = h_protein[r0*HF+idx];
        __syncthreads();
        float aA[8], aV[8], aC[8];
        const float bV = vb1[n];
        #pragma unroll
        for (int r=0;r<8;++r){ aA[r]=0.f; aV[r]=bV; aC[r]=0.f; }
        #pragma unroll 2
        for (int k=0;k<HF;++k){
            float wA = aW1[(HF+k)*HF+n], wV = vW1[k*HF+n], wC = cW1[(HF+k)*HF+n];
            #pragma unroll
            for (int r=0;r<8;++r){
                float h = rows[r][k];
                aA[r]=fmaf(h,wA,aA[r]); aV[r]=fmaf(h,wV,aV[r]); aC[r]=fmaf(h,wC,aC[r]);
            }
        }
        #pragma unroll
        for (int r=0;r<8;++r){
            Ap[(r0+r)*HF+n]=f2bf(aA[r]); Vp[(r0+r)*HF+n]=f2bf(aV[r]); Cp[(r0+r)*HF+n]=f2bf(aC[r]);
        }
    } else {
        const int m = blk - 576;         // 0..15: 8 blocks aW2, 8 blocks vW2
        const float* W = (m<8) ? aW2 : vW2;
        unsigned short* WT = (m<8) ? WaT : WvT;
        const int n0 = (m&7)*16;
        #pragma unroll
        for (int kb=0; kb<16; ++kb) {
            int k = kb*8 + (n>>4);
            int col = n0 + (n&15);
            WT[col*HF + k] = f2bf(W[k*HF + col]);
        }
    }
}

// ---------------------------------------------------------------------------
// Main fused kernel: grid = 1024 blocks = (b,i,jhalf); 256 threads = 4 waves.
// Edge-compaction of the 512-j range, then barrier-free main loop:
// each wave owns 16 rows x full n=128; A/V fragments built in registers,
// weight B-fragments streamed from L2 (bf16 W^T).  attn reduced via shfl.
// __launch_bounds__(256,2): round-4's (256,4) clamped VGPRs to 64 and spilled
// 1.8 GB/launch to scratch — never cap below the kernel's ~130-reg demand.
// ---------------------------------------------------------------------------
__global__ __launch_bounds__(256,2) void egnn_main_kernel(
    const float* __restrict__ x_ligand, const float* __restrict__ x_protein,
    const float* __restrict__ ligand_mask, const float* __restrict__ protein_mask,
    const float* __restrict__ aW1, const float* __restrict__ ab2,
    const float* __restrict__ aW3, const float* __restrict__ ab3,
    const float* __restrict__ vW1, const float* __restrict__ vb2,
    const float* __restrict__ cW1, const float* __restrict__ cW2, const float* __restrict__ cb2,
    const float* __restrict__ Al, const float* __restrict__ Cl,
    const unsigned short* __restrict__ Ap, const unsigned short* __restrict__ Vp,
    const unsigned short* __restrict__ Cp,
    const unsigned short* __restrict__ WaT, const unsigned short* __restrict__ WvT,
    float* __restrict__ out)
{
    __shared__ float ds_all[512], pme[512], dirx[512], diry[512], dirz[512];
    __shared__ unsigned short jlist[512];
    __shared__ float Al_s[HF], aw1l[HF], vw1l[HF];
    __shared__ float Cl_s[HF], cw1l[HF], cW2s[HF];
    __shared__ float2 aa3[HF];          // {ab2, aW3}
    __shared__ float vb2s[HF];
    __shared__ float hred[4][HF];
    __shared__ float xw[4][3];
    __shared__ int nact_s;

    const int t = threadIdx.x, lane = t&63, w = t>>6;
    const int lr = lane&15, lg = lane>>4;
    const int bi = blockIdx.x;
    const int half = bi & 1;
    const int ii = bi >> 1;              // b*128 + i
    const int b = ii >> 7;
    const int jbase = half*512;

    // ---- prologue: constants ----
    if (t < HF) {
        Al_s[t] = Al[(size_t)ii*HF+t];
        Cl_s[t] = Cl[(size_t)ii*HF+t];
        aw1l[t] = aW1[256*HF+t];
        cw1l[t] = cW1[256*HF+t];
        vw1l[t] = vW1[128*HF+t];
        cW2s[t] = cW2[t];
        vb2s[t] = vb2[t];
        aa3[t]  = make_float2(ab2[t], aW3[t]);
    }
    // ---- prologue: geometry for 512 j ----
    const float xl0 = x_ligand[ii*3+0], xl1 = x_ligand[ii*3+1], xl2 = x_ligand[ii*3+2];
    const float* xp = x_protein + ((size_t)b*NP + jbase)*3;
    const float* pm = protein_mask + (size_t)b*NP + jbase;
    #pragma unroll
    for (int q=0; q<2; ++q) {
        int jj = q*256 + t;
        float r0 = xl0-xp[jj*3+0], r1 = xl1-xp[jj*3+1], r2 = xl2-xp[jj*3+2];
        float ds = r0*r0+r1*r1+r2*r2;
        float dist = sqrtf(ds+EPSF);
        float inv = fast_rcp(dist+EPSF);
        float e = dist < 10.f ? 1.f : 0.f;
        ds_all[jj]=ds; pme[jj]=pm[jj]*e;
        dirx[jj]=r0*inv; diry[jj]=r1*inv; dirz[jj]=r2*inv;
    }
    __syncthreads();
    // ---- compaction (wave 0) ----
    if (w == 0) {
        int base = 0;
        for (int c=0; c<8; ++c) {
            int jj = c*64 + lane;
            bool act = pme[jj] > 0.f;
            unsigned long long m = __ballot(act);
            int pos = base + __popcll(m & ((1ull<<lane)-1ull));
            if (act) jlist[pos] = (unsigned short)jj;
            base += __popcll(m);
        }
        if (lane == 0) nact_s = base;
    }
    __syncthreads();
    const int nact = nact_s;
    const int ntiles = (nact + 63) >> 6;

    const unsigned short* Ap_b = Ap + ((size_t)b*NP + jbase)*HF;
    const unsigned short* Vp_b = Vp + ((size_t)b*NP + jbase)*HF;
    const unsigned short* Cp_b = Cp + ((size_t)b*NP + jbase)*HF;
    const float ab3v = ab3[0], cb2v = cb2[0];

    float hacc[8] = {0.f,0.f,0.f,0.f,0.f,0.f,0.f,0.f};
    float sae = 0.f;
    float xa0 = 0.f, xa1 = 0.f, xa2 = 0.f;
    const int crow = t >> 2, cg = t & 3;   // c-branch: row 0..63, group 0..3 (32 ch)

    for (int tile = 0; tile < ntiles; ++tile) {
        const int j0 = tile*64;

        // ---- A-fragments in registers: rows w*16+lr, k-chunk lg ----
        const int grow = j0 + w*16 + lr;
        const bool ok = grow < nact;
        const int jl = jlist[ok ? grow : 0];
        const float dsv = ds_all[jl];
        bf16x8 af[4];
        #pragma unroll
        for (int ks=0; ks<4; ++ks) {
            const int ch = ks*32 + lg*8;
            bf16x8 ap = *(const bf16x8*)(Ap_b + (size_t)jl*HF + ch);
            f32x4 al0 = *(const f32x4*)&Al_s[ch];
            f32x4 al1 = *(const f32x4*)&Al_s[ch+4];
            f32x4 w0  = *(const f32x4*)&aw1l[ch];
            f32x4 w1  = *(const f32x4*)&aw1l[ch+4];
            bf16x8 o;
            #pragma unroll
            for (int q=0;q<4;++q) {
                o[q]   = (short)f2bf(silu_f(al0[q] + bf2f(ap[q])   + dsv*w0[q]));
                o[q+4] = (short)f2bf(silu_f(al1[q] + bf2f(ap[q+4]) + dsv*w1[q]));
            }
            af[ks] = o;
        }
        // ---- a-GEMM: stream aW2^T B-frags from L2 ----
        f32x4 acc[8];
        #pragma unroll
        for (int nt=0; nt<8; ++nt) {
            const unsigned short* wp = WaT + (size_t)(nt*16+lr)*HF + lg*8;
            f32x4 a = {0.f,0.f,0.f,0.f};
            #pragma unroll
            for (int ks=0; ks<4; ++ks) {
                bf16x8 wb = *(const bf16x8*)(wp + ks*32);
                a = __builtin_amdgcn_mfma_f32_16x16x32_bf16(af[ks], wb, a, 0,0,0);
            }
            acc[nt] = a;
        }
        // ---- attn epilogue (all in-wave) ----
        float ae[4];
        #pragma unroll
        for (int r=0; r<4; ++r) {
            float p = 0.f;
            #pragma unroll
            for (int nt=0; nt<8; ++nt) {
                float2 c2 = aa3[nt*16+lr];
                p += silu_f(acc[nt][r] + c2.x) * c2.y;
            }
            p += __shfl_xor(p,1); p += __shfl_xor(p,2);
            p += __shfl_xor(p,4); p += __shfl_xor(p,8);
            const int growr = j0 + w*16 + lg*4 + r;
            const bool okr = growr < nact;
            const int jlr = jlist[okr ? growr : 0];
            const float pmer = okr ? pme[jlr] : 0.f;
            ae[r] = sigmoid_f(p + ab3v) * pmer;
            sae += ae[r];
        }
        // ---- V-fragments + v-GEMM, fold into hacc ----
        bf16x8 vf[4];
        #pragma unroll
        for (int ks=0; ks<4; ++ks) {
            const int ch = ks*32 + lg*8;
            bf16x8 vp = *(const bf16x8*)(Vp_b + (size_t)jl*HF + ch);
            f32x4 w0 = *(const f32x4*)&vw1l[ch];
            f32x4 w1 = *(const f32x4*)&vw1l[ch+4];
            bf16x8 o;
            #pragma unroll
            for (int q=0;q<4;++q) {
                o[q]   = (short)f2bf(silu_f(bf2f(vp[q])   + dsv*w0[q]));
                o[q+4] = (short)f2bf(silu_f(bf2f(vp[q+4]) + dsv*w1[q]));
            }
            vf[ks] = o;
        }
        #pragma unroll
        for (int nt=0; nt<8; ++nt) {
            const unsigned short* wp = WvT + (size_t)(nt*16+lr)*HF + lg*8;
            f32x4 a = {0.f,0.f,0.f,0.f};
            #pragma unroll
            for (int ks=0; ks<4; ++ks) {
                bf16x8 wb = *(const bf16x8*)(wp + ks*32);
                a = __builtin_amdgcn_mfma_f32_16x16x32_bf16(vf[ks], wb, a, 0,0,0);
            }
            hacc[nt] += ae[0]*a[0] + ae[1]*a[1] + ae[2]*a[2] + ae[3]*a[3];
        }
        // ---- c-branch (VALU) ----
        {
            const int growc = j0 + crow;
            const bool okc = growc < nact;
            const int jlc = jlist[okc ? growc : 0];
            const float pmec = okc ? pme[jlc] : 0.f;
            const float dsc = ds_all[jlc];
            float part = 0.f;
            const unsigned short* cp = Cp_b + (size_t)jlc*HF + cg*32;
            #pragma unroll
            for (int u=0; u<4; ++u) {
                const int ch = cg*32 + u*8;
                bf16x8 cv = *(const bf16x8*)(cp + u*8);
                f32x4 cl0 = *(const f32x4*)&Cl_s[ch];
                f32x4 cl1 = *(const f32x4*)&Cl_s[ch+4];
                f32x4 w0  = *(const f32x4*)&cw1l[ch];
                f32x4 w1  = *(const f32x4*)&cw1l[ch+4];
                f32x4 s0  = *(const f32x4*)&cW2s[ch];
                f32x4 s1  = *(const f32x4*)&cW2s[ch+4];
                #pragma unroll
                for (int q=0;q<4;++q) {
                    part += silu_f(cl0[q] + bf2f(cv[q])   + dsc*w0[q]) * s0[q];
                    part += silu_f(cl1[q] + bf2f(cv[q+4]) + dsc*w1[q]) * s1[q];
                }
            }
            part += __shfl_xor(part,1); part += __shfl_xor(part,2);
            if (cg == 0) {
                float cw = tanh_f(part + cb2v) * pmec;
                xa0 = fmaf(dirx[jlc], cw, xa0);
                xa1 = fmaf(diry[jlc], cw, xa1);
                xa2 = fmaf(dirz[jlc], cw, xa2);
            }
        }
    }

    // ---- final reductions ----
    #pragma unroll
    for (int nt=0; nt<8; ++nt) {
        hacc[nt] += __shfl_xor(hacc[nt],16);
        hacc[nt] += __shfl_xor(hacc[nt],32);
    }
    sae += __shfl_xor(sae,16);
    sae += __shfl_xor(sae,32);
    if (lg == 0) {
        #pragma unroll
        for (int nt=0; nt<8; ++nt)
            hred[w][nt*16+lr] = hacc[nt] + vb2s[nt*16+lr]*sae;
    }
    xa0 += __shfl_xor(xa0,1);  xa1 += __shfl_xor(xa1,1);  xa2 += __shfl_xor(xa2,1);
    xa0 += __shfl_xor(xa0,2);  xa1 += __shfl_xor(xa1,2);  xa2 += __shfl_xor(xa2,2);
    xa0 += __shfl_xor(xa0,4);  xa1 += __shfl_xor(xa1,4);  xa2 += __shfl_xor(xa2,4);
    xa0 += __shfl_xor(xa0,8);  xa1 += __shfl_xor(xa1,8);  xa2 += __shfl_xor(xa2,8);
    xa0 += __shfl_xor(xa0,16); xa1 += __shfl_xor(xa1,16); xa2 += __shfl_xor(xa2,16);
    xa0 += __shfl_xor(xa0,32); xa1 += __shfl_xor(xa1,32); xa2 += __shfl_xor(xa2,32);
    if (lane == 0) { xw[w][0]=xa0; xw[w][1]=xa1; xw[w][2]=xa2; }
    __syncthreads();

    const float lm = ligand_mask[ii];
    if (t < HF) {
        float v = (hred[0][t]+hred[1][t]+hred[2][t]+hred[3][t]) * 0.01f * lm;
        atomicAdd(&out[(size_t)ii*HF + t], v);
    }
    if (t < 3) {
        float v = (xw[0][t]+xw[1][t]+xw[2][t]+xw[3][t]) * 0.01f * lm;
        atomicAdd(&out[(size_t)NB*NL*HF + ii*3 + t], v);
    }
}

extern "C" void kernel_launch(void* const* d_in, const int* in_sizes, int n_in,
                              void* d_out, int out_size, void* d_ws, size_t ws_size,
                              hipStream_t stream) {
    const float* h_ligand     = (const float*)d_in[0];
    const float* x_ligand     = (const float*)d_in[1];
    const float* h_protein    = (const float*)d_in[2];
    const float* x_protein    = (const float*)d_in[3];
    const float* ligand_mask  = (const float*)d_in[4];
    const float* protein_mask = (const float*)d_in[5];
    const float* aW1 = (const float*)d_in[6];
    const float* ab1 = (const float*)d_in[7];
    const float* aW2 = (const float*)d_in[8];
    const float* ab2 = (const float*)d_in[9];
    const float* aW3 = (const float*)d_in[10];
    const float* ab3 = (const float*)d_in[11];
    const float* vW1 = (const float*)d_in[12];
    const float* vb1 = (const float*)d_in[13];
    const float* vW2 = (const float*)d_in[14];
    const float* vb2 = (const float*)d_in[15];
    const float* cW1 = (const float*)d_in[16];
    const float* cb1 = (const float*)d_in[17];
    const float* cW2 = (const float*)d_in[18];
    const float* cb2 = (const float*)d_in[19];

    // workspace layout (all chunks 256B-aligned)
    float* Al = (float*)d_ws;                              // 512*128 f32
    float* Cl = Al + 512*HF;                               // 512*128 f32
    unsigned short* Ap  = (unsigned short*)(Cl + 512*HF);  // 4096*128 bf16
    unsigned short* Vp  = Ap + (size_t)NB*NP*HF;
    unsigned short* Cp  = Vp + (size_t)NB*NP*HF;
    unsigned short* WaT = Cp + (size_t)NB*NP*HF;           // 128*128 bf16
    unsigned short* WvT = WaT + HF*HF;

    hipMemsetAsync(d_out, 0, (size_t)out_size*sizeof(float), stream);

    precompute_kernel<<<592, 128, 0, stream>>>(
        h_ligand, h_protein, aW1, ab1, vW1, vb1, cW1, cb1, aW2, vW2,
        Al, Cl, Ap, Vp, Cp, WaT, WvT);

    egnn_main_kernel<<<NB*NL*2, 256, 0, stream>>>(
        x_ligand, x_protein, ligand_mask, protein_mask,
        aW1, ab2, aW3, ab3, vW1, vb2, cW1, cW2, cb2,
        Al, Cl, Ap, Vp, Cp, WaT, WvT, (float*)d_out);
}

// Round 6
// 457.072 us; speedup vs baseline: 2.0240x; 1.2336x over previous
//
#include <hip/hip_runtime.h>
#include <hip/hip_bf16.h>
#include <math.h>

#define HF 128
#define NL 128
#define NP 1024
#define NB 4
#define EPSF 1e-8f

typedef short bf16x8 __attribute__((ext_vector_type(8)));
typedef float f32x4 __attribute__((ext_vector_type(4)));

__device__ __forceinline__ float fast_rcp(float x){ return __builtin_amdgcn_rcpf(x); }
__device__ __forceinline__ float silu_f(float x){ return x*fast_rcp(1.f+__expf(-x)); }
__device__ __forceinline__ float sigmoid_f(float x){ return fast_rcp(1.f+__expf(-x)); }
__device__ __forceinline__ float tanh_f(float x){ return 1.f - 2.f*fast_rcp(1.f+__expf(2.f*x)); }
__device__ __forceinline__ unsigned short f2bf(float f){ __hip_bfloat16 h=__float2bfloat16(f); return *(unsigned short*)&h; }
__device__ __forceinline__ float bf2f(short u){ unsigned int x = ((unsigned int)(unsigned short)u)<<16; float r; __builtin_memcpy(&r,&x,4); return r; }

// ---------------------------------------------------------------------------
// Precompute (unchanged):
//   Al = hl@aW1[0:128]+ab1 (f32), Cl = hl@cW1[0:128]+cb1 (f32)
//   Ap = hp@aW1[128:256] (bf16), Vp = hp@vW1[0:128]+vb1 (bf16), Cp = hp@cW1[128:256] (bf16)
//   WaT/WvT = aW2^T / vW2^T as bf16 [n][k]
// ---------------------------------------------------------------------------
__global__ __launch_bounds__(128) void precompute_kernel(
    const float* __restrict__ h_ligand, const float* __restrict__ h_protein,
    const float* __restrict__ aW1, const float* __restrict__ ab1,
    const float* __restrict__ vW1, const float* __restrict__ vb1,
    const float* __restrict__ cW1, const float* __restrict__ cb1,
    const float* __restrict__ aW2, const float* __restrict__ vW2,
    float* __restrict__ Al, float* __restrict__ Cl,
    unsigned short* __restrict__ Ap, unsigned short* __restrict__ Vp,
    unsigned short* __restrict__ Cp,
    unsigned short* __restrict__ WaT, unsigned short* __restrict__ WvT)
{
    const int blk = blockIdx.x, n = threadIdx.x;
    if (blk < 64) {
        __shared__ float rows[8][HF];
        const int r0 = blk*8;
        for (int idx=n; idx<8*HF; idx+=128) rows[idx>>7][idx&127] = h_ligand[r0*HF+idx];
        __syncthreads();
        float aA[8], aC[8];
        const float bA = ab1[n], bC = cb1[n];
        #pragma unroll
        for (int r=0;r<8;++r){ aA[r]=bA; aC[r]=bC; }
        #pragma unroll 4
        for (int k=0;k<HF;++k){
            float wA = aW1[k*HF+n], wC = cW1[k*HF+n];
            #pragma unroll
            for (int r=0;r<8;++r){ aA[r]=fmaf(rows[r][k],wA,aA[r]); aC[r]=fmaf(rows[r][k],wC,aC[r]); }
        }
        #pragma unroll
        for (int r=0;r<8;++r){ Al[(r0+r)*HF+n]=aA[r]; Cl[(r0+r)*HF+n]=aC[r]; }
    } else if (blk < 576) {
        __shared__ float rows[8][HF];
        const int r0 = (blk-64)*8;
        for (int idx=n; idx<8*HF; idx+=128) rows[idx>>7][idx&127] = h_protein[r0*HF+idx];
        __syncthreads();
        float aA[8], aV[8], aC[8];
        const float bV = vb1[n];
        #pragma unroll
        for (int r=0;r<8;++r){ aA[r]=0.f; aV[r]=bV; aC[r]=0.f; }
        #pragma unroll 2
        for (int k=0;k<HF;++k){
            float wA = aW1[(HF+k)*HF+n], wV = vW1[k*HF+n], wC = cW1[(HF+k)*HF+n];
            #pragma unroll
            for (int r=0;r<8;++r){
                float h = rows[r][k];
                aA[r]=fmaf(h,wA,aA[r]); aV[r]=fmaf(h,wV,aV[r]); aC[r]=fmaf(h,wC,aC[r]);
            }
        }
        #pragma unroll
        for (int r=0;r<8;++r){
            Ap[(r0+r)*HF+n]=f2bf(aA[r]); Vp[(r0+r)*HF+n]=f2bf(aV[r]); Cp[(r0+r)*HF+n]=f2bf(aC[r]);
        }
    } else {
        const int m = blk - 576;         // 0..15: 8 blocks aW2, 8 blocks vW2
        const float* W = (m<8) ? aW2 : vW2;
        unsigned short* WT = (m<8) ? WaT : WvT;
        const int n0 = (m&7)*16;
        #pragma unroll
        for (int kb=0; kb<16; ++kb) {
            int k = kb*8 + (n>>4);
            int col = n0 + (n&15);
            WT[col*HF + k] = f2bf(W[k*HF + col]);
        }
    }
}

// ---------------------------------------------------------------------------
// Main fused kernel: grid = 1024 blocks = (b,i,jhalf); 256 threads = 4 waves.
// Edge-compaction, then barrier-free loop over 128-row j-tiles:
// two 64-row sub-GEMMs share each streamed weight B-frag (halves L2 weight
// traffic); a-GEMM accumulator folded per-nt into p[] (no acc[8] live block
// -> no scratch spill; round-5's spill was 1.2 GB/dispatch).
// ---------------------------------------------------------------------------
__global__ __launch_bounds__(256,2) void egnn_main_kernel(
    const float* __restrict__ x_ligand, const float* __restrict__ x_protein,
    const float* __restrict__ ligand_mask, const float* __restrict__ protein_mask,
    const float* __restrict__ aW1, const float* __restrict__ ab2,
    const float* __restrict__ aW3, const float* __restrict__ ab3,
    const float* __restrict__ vW1, const float* __restrict__ vb2,
    const float* __restrict__ cW1, const float* __restrict__ cW2, const float* __restrict__ cb2,
    const float* __restrict__ Al, const float* __restrict__ Cl,
    const unsigned short* __restrict__ Ap, const unsigned short* __restrict__ Vp,
    const unsigned short* __restrict__ Cp,
    const unsigned short* __restrict__ WaT, const unsigned short* __restrict__ WvT,
    float* __restrict__ out)
{
    __shared__ float ds_all[512], pme[512], dirx[512], diry[512], dirz[512];
    __shared__ unsigned short jlist[512];
    __shared__ float Al_s[HF], aw1l[HF], vw1l[HF];
    __shared__ float Cl_s[HF], cw1l[HF], cW2s[HF];
    __shared__ float2 aa3[HF];          // {ab2, aW3}
    __shared__ float vb2s[HF];
    __shared__ float hred[4][HF];
    __shared__ float xw[4][3];
    __shared__ int nact_s;

    const int t = threadIdx.x, lane = t&63, w = t>>6;
    const int lr = lane&15, lg = lane>>4;
    const int bi = blockIdx.x;
    const int half = bi & 1;
    const int ii = bi >> 1;              // b*128 + i
    const int b = ii >> 7;
    const int jbase = half*512;

    // ---- prologue: constants ----
    if (t < HF) {
        Al_s[t] = Al[(size_t)ii*HF+t];
        Cl_s[t] = Cl[(size_t)ii*HF+t];
        aw1l[t] = aW1[256*HF+t];
        cw1l[t] = cW1[256*HF+t];
        vw1l[t] = vW1[128*HF+t];
        cW2s[t] = cW2[t];
        vb2s[t] = vb2[t];
        aa3[t]  = make_float2(ab2[t], aW3[t]);
    }
    // ---- prologue: geometry for 512 j ----
    const float xl0 = x_ligand[ii*3+0], xl1 = x_ligand[ii*3+1], xl2 = x_ligand[ii*3+2];
    const float* xp = x_protein + ((size_t)b*NP + jbase)*3;
    const float* pm = protein_mask + (size_t)b*NP + jbase;
    #pragma unroll
    for (int q=0; q<2; ++q) {
        int jj = q*256 + t;
        float r0 = xl0-xp[jj*3+0], r1 = xl1-xp[jj*3+1], r2 = xl2-xp[jj*3+2];
        float ds = r0*r0+r1*r1+r2*r2;
        float dist = sqrtf(ds+EPSF);
        float inv = fast_rcp(dist+EPSF);
        float e = dist < 10.f ? 1.f : 0.f;
        ds_all[jj]=ds; pme[jj]=pm[jj]*e;
        dirx[jj]=r0*inv; diry[jj]=r1*inv; dirz[jj]=r2*inv;
    }
    __syncthreads();
    // ---- compaction (wave 0) ----
    if (w == 0) {
        int base = 0;
        for (int c=0; c<8; ++c) {
            int jj = c*64 + lane;
            bool act = pme[jj] > 0.f;
            unsigned long long m = __ballot(act);
            int pos = base + __popcll(m & ((1ull<<lane)-1ull));
            if (act) jlist[pos] = (unsigned short)jj;
            base += __popcll(m);
        }
        if (lane == 0) nact_s = base;
    }
    __syncthreads();
    const int nact = nact_s;
    const int ntiles = (nact + 127) >> 7;

    const unsigned short* Ap_b = Ap + ((size_t)b*NP + jbase)*HF;
    const unsigned short* Vp_b = Vp + ((size_t)b*NP + jbase)*HF;
    const unsigned short* Cp_b = Cp + ((size_t)b*NP + jbase)*HF;
    const float ab3v = ab3[0], cb2v = cb2[0];

    float hacc[8] = {0.f,0.f,0.f,0.f,0.f,0.f,0.f,0.f};
    float sae = 0.f;
    float xa0 = 0.f, xa1 = 0.f, xa2 = 0.f;
    const int crow = t >> 2, cg = t & 3;   // c-branch: row 0..63, group 0..3 (32 ch)

    for (int tile = 0; tile < ntiles; ++tile) {
        const int j0 = tile*128;

        // ---- rows for the two 64-row sub-GEMMs ----
        const int grow0 = j0 + w*16 + lr;
        const int grow1 = grow0 + 64;
        const bool ok0 = grow0 < nact, ok1 = grow1 < nact;
        const int jl0 = jlist[ok0 ? grow0 : 0];
        const int jl1 = jlist[ok1 ? grow1 : 0];
        const float dsv0 = ds_all[jl0], dsv1 = ds_all[jl1];

        // ---- A-fragments in registers (row = lr, k-chunk = lg) ----
        bf16x8 af0[4], af1[4];
        #pragma unroll
        for (int ks=0; ks<4; ++ks) {
            const int ch = ks*32 + lg*8;
            bf16x8 ap0 = *(const bf16x8*)(Ap_b + (size_t)jl0*HF + ch);
            bf16x8 ap1 = *(const bf16x8*)(Ap_b + (size_t)jl1*HF + ch);
            f32x4 al0 = *(const f32x4*)&Al_s[ch];
            f32x4 al1 = *(const f32x4*)&Al_s[ch+4];
            f32x4 w0  = *(const f32x4*)&aw1l[ch];
            f32x4 w1  = *(const f32x4*)&aw1l[ch+4];
            bf16x8 o0, o1;
            #pragma unroll
            for (int q=0;q<4;++q) {
                o0[q]   = (short)f2bf(silu_f(al0[q] + bf2f(ap0[q])   + dsv0*w0[q]));
                o0[q+4] = (short)f2bf(silu_f(al1[q] + bf2f(ap0[q+4]) + dsv0*w1[q]));
                o1[q]   = (short)f2bf(silu_f(al0[q] + bf2f(ap1[q])   + dsv1*w0[q]));
                o1[q+4] = (short)f2bf(silu_f(al1[q] + bf2f(ap1[q+4]) + dsv1*w1[q]));
            }
            af0[ks] = o0; af1[ks] = o1;
        }
        // ---- a-GEMM: stream aW2^T B-frags once, feed both subs; fold per-nt ----
        float p0[4] = {0.f,0.f,0.f,0.f}, p1[4] = {0.f,0.f,0.f,0.f};
        #pragma unroll
        for (int nt=0; nt<8; ++nt) {
            const unsigned short* wp = WaT + (size_t)(nt*16+lr)*HF + lg*8;
            f32x4 a0 = {0.f,0.f,0.f,0.f}, a1 = {0.f,0.f,0.f,0.f};
            #pragma unroll
            for (int ks=0; ks<4; ++ks) {
                bf16x8 wb = *(const bf16x8*)(wp + ks*32);
                a0 = __builtin_amdgcn_mfma_f32_16x16x32_bf16(af0[ks], wb, a0, 0,0,0);
                a1 = __builtin_amdgcn_mfma_f32_16x16x32_bf16(af1[ks], wb, a1, 0,0,0);
            }
            float2 c2 = aa3[nt*16+lr];
            #pragma unroll
            for (int r=0; r<4; ++r) {
                p0[r] += silu_f(a0[r] + c2.x) * c2.y;
                p1[r] += silu_f(a1[r] + c2.x) * c2.y;
            }
        }
        // ---- attn: reduce over n (lr lanes), sigmoid, gate ----
        float ae0[4], ae1[4];
        #pragma unroll
        for (int r=0; r<4; ++r) {
            float q0 = p0[r], q1 = p1[r];
            q0 += __shfl_xor(q0,1); q1 += __shfl_xor(q1,1);
            q0 += __shfl_xor(q0,2); q1 += __shfl_xor(q1,2);
            q0 += __shfl_xor(q0,4); q1 += __shfl_xor(q1,4);
            q0 += __shfl_xor(q0,8); q1 += __shfl_xor(q1,8);
            const int gr0 = j0 + w*16 + lg*4 + r;
            const int gr1 = gr0 + 64;
            const bool okr0 = gr0 < nact, okr1 = gr1 < nact;
            const float pm0 = okr0 ? pme[jlist[okr0 ? gr0 : 0]] : 0.f;
            const float pm1 = okr1 ? pme[jlist[okr1 ? gr1 : 0]] : 0.f;
            ae0[r] = sigmoid_f(q0 + ab3v) * pm0;
            ae1[r] = sigmoid_f(q1 + ab3v) * pm1;
            sae += ae0[r] + ae1[r];
        }
        // ---- V-fragments (reuse af register space) + v-GEMM ----
        bf16x8 vf0[4], vf1[4];
        #pragma unroll
        for (int ks=0; ks<4; ++ks) {
            const int ch = ks*32 + lg*8;
            bf16x8 vp0 = *(const bf16x8*)(Vp_b + (size_t)jl0*HF + ch);
            bf16x8 vp1 = *(const bf16x8*)(Vp_b + (size_t)jl1*HF + ch);
            f32x4 w0 = *(const f32x4*)&vw1l[ch];
            f32x4 w1 = *(const f32x4*)&vw1l[ch+4];
            bf16x8 o0, o1;
            #pragma unroll
            for (int q=0;q<4;++q) {
                o0[q]   = (short)f2bf(silu_f(bf2f(vp0[q])   + dsv0*w0[q]));
                o0[q+4] = (short)f2bf(silu_f(bf2f(vp0[q+4]) + dsv0*w1[q]));
                o1[q]   = (short)f2bf(silu_f(bf2f(vp1[q])   + dsv1*w0[q]));
                o1[q+4] = (short)f2bf(silu_f(bf2f(vp1[q+4]) + dsv1*w1[q]));
            }
            vf0[ks] = o0; vf1[ks] = o1;
        }
        #pragma unroll
        for (int nt=0; nt<8; ++nt) {
            const unsigned short* wp = WvT + (size_t)(nt*16+lr)*HF + lg*8;
            f32x4 a0 = {0.f,0.f,0.f,0.f}, a1 = {0.f,0.f,0.f,0.f};
            #pragma unroll
            for (int ks=0; ks<4; ++ks) {
                bf16x8 wb = *(const bf16x8*)(wp + ks*32);
                a0 = __builtin_amdgcn_mfma_f32_16x16x32_bf16(vf0[ks], wb, a0, 0,0,0);
                a1 = __builtin_amdgcn_mfma_f32_16x16x32_bf16(vf1[ks], wb, a1, 0,0,0);
            }
            hacc[nt] += ae0[0]*a0[0] + ae0[1]*a0[1] + ae0[2]*a0[2] + ae0[3]*a0[3]
                      + ae1[0]*a1[0] + ae1[1]*a1[1] + ae1[2]*a1[2] + ae1[3]*a1[3];
        }
        // ---- c-branch (VALU): two 64-row passes ----
        #pragma unroll
        for (int p2=0; p2<2; ++p2) {
            const int growc = j0 + p2*64 + crow;
            const bool okc = growc < nact;
            const int jlc = jlist[okc ? growc : 0];
            const float pmec = okc ? pme[jlc] : 0.f;
            const float dsc = ds_all[jlc];
            float part = 0.f;
            const unsigned short* cp = Cp_b + (size_t)jlc*HF + cg*32;
            #pragma unroll
            for (int u=0; u<4; ++u) {
                const int ch = cg*32 + u*8;
                bf16x8 cv = *(const bf16x8*)(cp + u*8);
                f32x4 cl0 = *(const f32x4*)&Cl_s[ch];
                f32x4 cl1 = *(const f32x4*)&Cl_s[ch+4];
                f32x4 w0  = *(const f32x4*)&cw1l[ch];
                f32x4 w1  = *(const f32x4*)&cw1l[ch+4];
                f32x4 s0  = *(const f32x4*)&cW2s[ch];
                f32x4 s1  = *(const f32x4*)&cW2s[ch+4];
                #pragma unroll
                for (int q=0;q<4;++q) {
                    part += silu_f(cl0[q] + bf2f(cv[q])   + dsc*w0[q]) * s0[q];
                    part += silu_f(cl1[q] + bf2f(cv[q+4]) + dsc*w1[q]) * s1[q];
                }
            }
            part += __shfl_xor(part,1); part += __shfl_xor(part,2);
            if (cg == 0) {
                float cw = tanh_f(part + cb2v) * pmec;
                xa0 = fmaf(dirx[jlc], cw, xa0);
                xa1 = fmaf(diry[jlc], cw, xa1);
                xa2 = fmaf(dirz[jlc], cw, xa2);
            }
        }
    }

    // ---- final reductions ----
    #pragma unroll
    for (int nt=0; nt<8; ++nt) {
        hacc[nt] += __shfl_xor(hacc[nt],16);
        hacc[nt] += __shfl_xor(hacc[nt],32);
    }
    sae += __shfl_xor(sae,16);
    sae += __shfl_xor(sae,32);
    if (lg == 0) {
        #pragma unroll
        for (int nt=0; nt<8; ++nt)
            hred[w][nt*16+lr] = hacc[nt] + vb2s[nt*16+lr]*sae;
    }
    xa0 += __shfl_xor(xa0,1);  xa1 += __shfl_xor(xa1,1);  xa2 += __shfl_xor(xa2,1);
    xa0 += __shfl_xor(xa0,2);  xa1 += __shfl_xor(xa1,2);  xa2 += __shfl_xor(xa2,2);
    xa0 += __shfl_xor(xa0,4);  xa1 += __shfl_xor(xa1,4);  xa2 += __shfl_xor(xa2,4);
    xa0 += __shfl_xor(xa0,8);  xa1 += __shfl_xor(xa1,8);  xa2 += __shfl_xor(xa2,8);
    xa0 += __shfl_xor(xa0,16); xa1 += __shfl_xor(xa1,16); xa2 += __shfl_xor(xa2,16);
    xa0 += __shfl_xor(xa0,32); xa1 += __shfl_xor(xa1,32); xa2 += __shfl_xor(xa2,32);
    if (lane == 0) { xw[w][0]=xa0; xw[w][1]=xa1; xw[w][2]=xa2; }
    __syncthreads();

    const float lm = ligand_mask[ii];
    if (t < HF) {
        float v = (hred[0][t]+hred[1][t]+hred[2][t]+hred[3][t]) * 0.01f * lm;
        atomicAdd(&out[(size_t)ii*HF + t], v);
    }
    if (t < 3) {
        float v = (xw[0][t]+xw[1][t]+xw[2][t]+xw[3][t]) * 0.01f * lm;
        atomicAdd(&out[(size_t)NB*NL*HF + ii*3 + t], v);
    }
}

extern "C" void kernel_launch(void* const* d_in, const int* in_sizes, int n_in,
                              void* d_out, int out_size, void* d_ws, size_t ws_size,
                              hipStream_t stream) {
    const float* h_ligand     = (const float*)d_in[0];
    const float* x_ligand     = (const float*)d_in[1];
    const float* h_protein    = (const float*)d_in[2];
    const float* x_protein    = (const float*)d_in[3];
    const float* ligand_mask  = (const float*)d_in[4];
    const float* protein_mask = (const float*)d_in[5];
    const float* aW1 = (const float*)d_in[6];
    const float* ab1 = (const float*)d_in[7];
    const float* aW2 = (const float*)d_in[8];
    const float* ab2 = (const float*)d_in[9];
    const float* aW3 = (const float*)d_in[10];
    const float* ab3 = (const float*)d_in[11];
    const float* vW1 = (const float*)d_in[12];
    const float* vb1 = (const float*)d_in[13];
    const float* vW2 = (const float*)d_in[14];
    const float* vb2 = (const float*)d_in[15];
    const float* cW1 = (const float*)d_in[16];
    const float* cb1 = (const float*)d_in[17];
    const float* cW2 = (const float*)d_in[18];
    const float* cb2 = (const float*)d_in[19];

    // workspace layout (all chunks 256B-aligned)
    float* Al = (float*)d_ws;                              // 512*128 f32
    float* Cl = Al + 512*HF;                               // 512*128 f32
    unsigned short* Ap  = (unsigned short*)(Cl + 512*HF);  // 4096*128 bf16
    unsigned short* Vp  = Ap + (size_t)NB*NP*HF;
    unsigned short* Cp  = Vp + (size_t)NB*NP*HF;
    unsigned short* WaT = Cp + (size_t)NB*NP*HF;           // 128*128 bf16
    unsigned short* WvT = WaT + HF*HF;

    hipMemsetAsync(d_out, 0, (size_t)out_size*sizeof(float), stream);

    precompute_kernel<<<592, 128, 0, stream>>>(
        h_ligand, h_protein, aW1, ab1, vW1, vb1, cW1, cb1, aW2, vW2,
        Al, Cl, Ap, Vp, Cp, WaT, WvT);

    egnn_main_kernel<<<NB*NL*2, 256, 0, stream>>>(
        x_ligand, x_protein, ligand_mask, protein_mask,
        aW1, ab2, aW3, ab3, vW1, vb2, cW1, cW2, cb2,
        Al, Cl, Ap, Vp, Cp, WaT, WvT, (float*)d_out);
}

// Round 7
// 248.139 us; speedup vs baseline: 3.7282x; 1.8420x over previous
//
#include <hip/hip_runtime.h>
#include <hip/hip_bf16.h>
#include <math.h>

#define HF 128
#define NL 128
#define NP 1024
#define NB 4
#define EPSF 1e-8f

typedef short bf16x8 __attribute__((ext_vector_type(8)));
typedef float f32x4 __attribute__((ext_vector_type(4)));

__device__ __forceinline__ float fast_rcp(float x){ return __builtin_amdgcn_rcpf(x); }
__device__ __forceinline__ float silu_f(float x){ return x*fast_rcp(1.f+__expf(-x)); }
__device__ __forceinline__ float sigmoid_f(float x){ return fast_rcp(1.f+__expf(-x)); }
__device__ __forceinline__ float tanh_f(float x){ return 1.f - 2.f*fast_rcp(1.f+__expf(2.f*x)); }
__device__ __forceinline__ unsigned short f2bf(float f){ __hip_bfloat16 h=__float2bfloat16(f); return *(unsigned short*)&h; }
__device__ __forceinline__ float bf2f(short u){ unsigned int x = ((unsigned int)(unsigned short)u)<<16; float r; __builtin_memcpy(&r,&x,4); return r; }

// ---------------------------------------------------------------------------
// Precompute (unchanged from r6, proven):
//   Al = hl@aW1[0:128]+ab1 (f32), Cl = hl@cW1[0:128]+cb1 (f32)
//   Ap = hp@aW1[128:256] (bf16), Vp = hp@vW1[0:128]+vb1 (bf16), Cp = hp@cW1[128:256] (bf16)
//   WaT/WvT = aW2^T / vW2^T as bf16 [n][k]
// ---------------------------------------------------------------------------
__global__ __launch_bounds__(128) void precompute_kernel(
    const float* __restrict__ h_ligand, const float* __restrict__ h_protein,
    const float* __restrict__ aW1, const float* __restrict__ ab1,
    const float* __restrict__ vW1, const float* __restrict__ vb1,
    const float* __restrict__ cW1, const float* __restrict__ cb1,
    const float* __restrict__ aW2, const float* __restrict__ vW2,
    float* __restrict__ Al, float* __restrict__ Cl,
    unsigned short* __restrict__ Ap, unsigned short* __restrict__ Vp,
    unsigned short* __restrict__ Cp,
    unsigned short* __restrict__ WaT, unsigned short* __restrict__ WvT)
{
    const int blk = blockIdx.x, n = threadIdx.x;
    if (blk < 64) {
        __shared__ float rows[8][HF];
        const int r0 = blk*8;
        for (int idx=n; idx<8*HF; idx+=128) rows[idx>>7][idx&127] = h_ligand[r0*HF+idx];
        __syncthreads();
        float aA[8], aC[8];
        const float bA = ab1[n], bC = cb1[n];
        #pragma unroll
        for (int r=0;r<8;++r){ aA[r]=bA; aC[r]=bC; }
        #pragma unroll 4
        for (int k=0;k<HF;++k){
            float wA = aW1[k*HF+n], wC = cW1[k*HF+n];
            #pragma unroll
            for (int r=0;r<8;++r){ aA[r]=fmaf(rows[r][k],wA,aA[r]); aC[r]=fmaf(rows[r][k],wC,aC[r]); }
        }
        #pragma unroll
        for (int r=0;r<8;++r){ Al[(r0+r)*HF+n]=aA[r]; Cl[(r0+r)*HF+n]=aC[r]; }
    } else if (blk < 576) {
        __shared__ float rows[8][HF];
        const int r0 = (blk-64)*8;
        for (int idx=n; idx<8*HF; idx+=128) rows[idx>>7][idx&127] = h_protein[r0*HF+idx];
        __syncthreads();
        float aA[8], aV[8], aC[8];
        const float bV = vb1[n];
        #pragma unroll
        for (int r=0;r<8;++r){ aA[r]=0.f; aV[r]=bV; aC[r]=0.f; }
        #pragma unroll 2
        for (int k=0;k<HF;++k){
            float wA = aW1[(HF+k)*HF+n], wV = vW1[k*HF+n], wC = cW1[(HF+k)*HF+n];
            #pragma unroll
            for (int r=0;r<8;++r){
                float h = rows[r][k];
                aA[r]=fmaf(h,wA,aA[r]); aV[r]=fmaf(h,wV,aV[r]); aC[r]=fmaf(h,wC,aC[r]);
            }
        }
        #pragma unroll
        for (int r=0;r<8;++r){
            Ap[(r0+r)*HF+n]=f2bf(aA[r]); Vp[(r0+r)*HF+n]=f2bf(aV[r]); Cp[(r0+r)*HF+n]=f2bf(aC[r]);
        }
    } else {
        const int m = blk - 576;
        const float* W = (m<8) ? aW2 : vW2;
        unsigned short* WT = (m<8) ? WaT : WvT;
        const int n0 = (m&7)*16;
        #pragma unroll
        for (int kb=0; kb<16; ++kb) {
            int k = kb*8 + (n>>4);
            int col = n0 + (n&15);
            WT[col*HF + k] = f2bf(W[k*HF + col]);
        }
    }
}

// ---------------------------------------------------------------------------
// Main kernel, round-2 structure + compaction.  Grid = 1024 = (b,i,jhalf),
// 256 threads = 4 waves (2 wj x 2 wn).  Weights live in AGPR B-frags (zero
// spill: r2 proof).  A/V tiles (32 compacted j-rows x 128, bf16, swizzled)
// go through LDS; 3 barriers/tile.  Edge compaction cuts ~37% of all work.
// ---------------------------------------------------------------------------
__global__ __launch_bounds__(256,2) void egnn_main_kernel(
    const float* __restrict__ x_ligand, const float* __restrict__ x_protein,
    const float* __restrict__ ligand_mask, const float* __restrict__ protein_mask,
    const float* __restrict__ aW1, const float* __restrict__ ab2,
    const float* __restrict__ aW3, const float* __restrict__ ab3,
    const float* __restrict__ vW1, const float* __restrict__ vb2,
    const float* __restrict__ cW1, const float* __restrict__ cW2, const float* __restrict__ cb2,
    const float* __restrict__ Al, const float* __restrict__ Cl,
    const unsigned short* __restrict__ Ap, const unsigned short* __restrict__ Vp,
    const unsigned short* __restrict__ Cp,
    const unsigned short* __restrict__ WaT, const unsigned short* __restrict__ WvT,
    float* __restrict__ out)
{
    __shared__ __align__(16) char smem[50176];
    // lo region [0,32768): weight staging; later Abuf [0,8192), Vbuf [8192,16384)
    float* ds_all = (float*)(smem + 32768);            // [512]
    float* pme    = (float*)(smem + 34816);            // [512]
    float* dirx   = (float*)(smem + 36864);
    float* diry   = (float*)(smem + 38912);
    float* dirz   = (float*)(smem + 40960);
    unsigned short* jlist = (unsigned short*)(smem + 43008); // [512]
    float* Al_s   = (float*)(smem + 44032);            // [128] each
    float* Cl_s   = (float*)(smem + 44544);
    float* aw1l   = (float*)(smem + 45056);
    float* cw1l   = (float*)(smem + 45568);
    float* vw1l   = (float*)(smem + 46080);
    float* cW2s   = (float*)(smem + 46592);
    float* attn_part = (float*)(smem + 47104);         // [64]
    float* attn_e = (float*)(smem + 47360);            // [32]
    float* hred   = (float*)(smem + 47616);            // [256] = [2][128]
    float* xw     = (float*)(smem + 48640);            // [12]
    int* nact_p   = (int*)(smem + 48704);

    const int t = threadIdx.x, lane = t&63, w = t>>6;
    const int wj = w>>1, wn = w&1;
    const int lr = lane&15, lg = lane>>4;
    const int bi = blockIdx.x;
    const int half = bi & 1;
    const int ii = bi >> 1;
    const int b = ii >> 7;
    const int jbase = half*512;

    // ---- prologue: geometry (hi region) + consts; stage WaT (lo region) ----
    const float xl0 = x_ligand[ii*3+0], xl1 = x_ligand[ii*3+1], xl2 = x_ligand[ii*3+2];
    const float* xp = x_protein + ((size_t)b*NP + jbase)*3;
    const float* pm = protein_mask + (size_t)b*NP + jbase;
    #pragma unroll
    for (int q=0; q<2; ++q) {
        int jj = q*256 + t;
        float r0 = xl0-xp[jj*3+0], r1 = xl1-xp[jj*3+1], r2 = xl2-xp[jj*3+2];
        float ds = r0*r0+r1*r1+r2*r2;
        float dist = sqrtf(ds+EPSF);
        float inv = fast_rcp(dist+EPSF);
        float e = dist < 10.f ? 1.f : 0.f;
        ds_all[jj]=ds; pme[jj]=pm[jj]*e;
        dirx[jj]=r0*inv; diry[jj]=r1*inv; dirz[jj]=r2*inv;
    }
    if (t < HF) {
        Al_s[t] = Al[(size_t)ii*HF+t];
        Cl_s[t] = Cl[(size_t)ii*HF+t];
        aw1l[t] = aW1[256*HF+t];
        cw1l[t] = cW1[256*HF+t];
        vw1l[t] = vW1[128*HF+t];
        cW2s[t] = cW2[t];
    }
    float ab2v[4], aw3v[4], vb2v[4];
    #pragma unroll
    for (int nt=0; nt<4; ++nt) {
        int n = wn*64 + nt*16 + lr;
        ab2v[nt] = ab2[n]; aw3v[nt] = aW3[n]; vb2v[nt] = vb2[n];
    }
    const float ab3v = ab3[0], cb2v = cb2[0];

    // stage WaT (2048 16B chunks)
    for (int c = t; c < 2048; c += 256) {
        int n = c >> 4, kc = c & 15;
        *(bf16x8*)(smem + n*256 + ((kc*16) ^ ((n&7)<<4))) = *(const bf16x8*)(WaT + n*HF + kc*8);
    }
    __syncthreads();   // WaT staged; geometry/pme ready

    // wave 0: compaction; all waves: load wa frags
    if (w == 0) {
        int base = 0;
        for (int c=0; c<8; ++c) {
            int jj = c*64 + lane;
            bool act = pme[jj] > 0.f;
            unsigned long long m = __ballot(act);
            int pos = base + __popcll(m & ((1ull<<lane)-1ull));
            if (act) jlist[pos] = (unsigned short)jj;
            base += __popcll(m);
        }
        if (lane == 0) *nact_p = base;
    }
    bf16x8 wa[4][4], wv[4][4];
    #pragma unroll
    for (int nt = 0; nt < 4; ++nt) {
        int ncol = wn*64 + nt*16 + lr;
        int rb = ncol*256, sw = (ncol & 7) << 4;
        #pragma unroll
        for (int ks = 0; ks < 4; ++ks)
            wa[nt][ks] = *(bf16x8*)(smem + rb + ((lg*16 + ks*64) ^ sw));
    }
    __syncthreads();   // all done reading WaT region

    for (int c = t; c < 2048; c += 256) {
        int n = c >> 4, kc = c & 15;
        *(bf16x8*)(smem + n*256 + ((kc*16) ^ ((n&7)<<4))) = *(const bf16x8*)(WvT + n*HF + kc*8);
    }
    __syncthreads();   // WvT staged
    #pragma unroll
    for (int nt = 0; nt < 4; ++nt) {
        int ncol = wn*64 + nt*16 + lr;
        int rb = ncol*256, sw = (ncol & 7) << 4;
        #pragma unroll
        for (int ks = 0; ks < 4; ++ks)
            wv[nt][ks] = *(bf16x8*)(smem + rb + ((lg*16 + ks*64) ^ sw));
    }
    __syncthreads();   // WvT read; lo region free for tiles; nact visible

    const int nact = *nact_p;
    const int ntiles = (nact + 31) >> 5;

    const unsigned short* Ap_b = Ap + ((size_t)b*NP + jbase)*HF;
    const unsigned short* Vp_b = Vp + ((size_t)b*NP + jbase)*HF;
    const unsigned short* Cp_b = Cp + ((size_t)b*NP + jbase)*HF;

    float hacc[4] = {0.f,0.f,0.f,0.f};
    float sae = 0.f;
    float xa0 = 0.f, xa1 = 0.f, xa2 = 0.f;
    const int brow = t >> 4, bcol = (t & 15)*8;   // tile build: 2 rows x 8 cols
    const int crow = t >> 3, cg = t & 7;          // c-branch: 32 rows x 8 groups

    for (int tile = 0; tile < ntiles; ++tile) {
        const int j0 = tile*32;

        // ---- phase 1: build A tile (compacted rows) ----
        #pragma unroll
        for (int m = 0; m < 2; ++m) {
            const int row = m*16 + brow;
            const int grow = j0 + row;
            const int jl = jlist[grow < nact ? grow : 0];
            const float dsv = ds_all[jl];
            bf16x8 ap = *(const bf16x8*)(Ap_b + (size_t)jl*HF + bcol);
            f32x4 al0 = *(const f32x4*)&Al_s[bcol];
            f32x4 al1 = *(const f32x4*)&Al_s[bcol+4];
            f32x4 w0  = *(const f32x4*)&aw1l[bcol];
            f32x4 w1  = *(const f32x4*)&aw1l[bcol+4];
            bf16x8 pk;
            #pragma unroll
            for (int q = 0; q < 4; ++q) {
                pk[q]   = (short)f2bf(silu_f(al0[q] + bf2f(ap[q])   + dsv*w0[q]));
                pk[q+4] = (short)f2bf(silu_f(al1[q] + bf2f(ap[q+4]) + dsv*w1[q]));
            }
            *(bf16x8*)(smem + row*256 + ((bcol*2) ^ ((row & 7) << 4))) = pk;
        }
        __syncthreads();   // bar 1: A ready

        // ---- phase 2: a-GEMM + attn partials; c-branch overlaps ----
        bf16x8 af[4];
        {
            int arow = wj*16 + lr;
            int rb = arow*256, sw = (arow & 7) << 4;
            #pragma unroll
            for (int ks = 0; ks < 4; ++ks)
                af[ks] = *(bf16x8*)(smem + rb + ((lg*16 + ks*64) ^ sw));
        }
        f32x4 acc[4];
        #pragma unroll
        for (int nt = 0; nt < 4; ++nt) {
            acc[nt] = (f32x4){0.f,0.f,0.f,0.f};
            #pragma unroll
            for (int ks = 0; ks < 4; ++ks)
                acc[nt] = __builtin_amdgcn_mfma_f32_16x16x32_bf16(af[ks], wa[nt][ks], acc[nt], 0,0,0);
        }
        // c-branch (VALU)
        {
            const int growc = j0 + crow;
            const bool okc = growc < nact;
            const int jlc = jlist[okc ? growc : 0];
            const float pmec = okc ? pme[jlc] : 0.f;
            const float dsc = ds_all[jlc];
            float part = 0.f;
            const unsigned short* cp = Cp_b + (size_t)jlc*HF + cg*16;
            #pragma unroll
            for (int u = 0; u < 2; ++u) {
                const int ch = cg*16 + u*8;
                bf16x8 cv = *(const bf16x8*)(cp + u*8);
                f32x4 cl0 = *(const f32x4*)&Cl_s[ch];
                f32x4 cl1 = *(const f32x4*)&Cl_s[ch+4];
                f32x4 w0  = *(const f32x4*)&cw1l[ch];
                f32x4 w1  = *(const f32x4*)&cw1l[ch+4];
                f32x4 s0  = *(const f32x4*)&cW2s[ch];
                f32x4 s1  = *(const f32x4*)&cW2s[ch+4];
                #pragma unroll
                for (int q = 0; q < 4; ++q) {
                    part += silu_f(cl0[q] + bf2f(cv[q])   + dsc*w0[q]) * s0[q];
                    part += silu_f(cl1[q] + bf2f(cv[q+4]) + dsc*w1[q]) * s1[q];
                }
            }
            part += __shfl_xor(part,1); part += __shfl_xor(part,2); part += __shfl_xor(part,4);
            if (cg == 0) {
                float cw = tanh_f(part + cb2v) * pmec;
                xa0 = fmaf(dirx[jlc], cw, xa0);
                xa1 = fmaf(diry[jlc], cw, xa1);
                xa2 = fmaf(dirz[jlc], cw, xa2);
            }
        }
        // attn epilogue: p = silu(a2+ab2).aW3 summed over this wave's 64 cols
        #pragma unroll
        for (int r = 0; r < 4; ++r) {
            float p = 0.f;
            #pragma unroll
            for (int nt = 0; nt < 4; ++nt)
                p += silu_f(acc[nt][r] + ab2v[nt]) * aw3v[nt];
            p += __shfl_xor(p,1); p += __shfl_xor(p,2);
            p += __shfl_xor(p,4); p += __shfl_xor(p,8);
            if (lr == 0) attn_part[wn*32 + wj*16 + lg*4 + r] = p;
        }
        __syncthreads();   // bar 2: attn_part ready

        // ---- phase 3: attn_e (t<32) + build V tile into Vbuf ----
        if (t < 32) {
            const int grow = j0 + t;
            const bool ok = grow < nact;
            const int j = jlist[ok ? grow : 0];
            attn_e[t] = sigmoid_f(attn_part[t] + attn_part[32+t] + ab3v) * (ok ? pme[j] : 0.f);
        }
        #pragma unroll
        for (int m = 0; m < 2; ++m) {
            const int row = m*16 + brow;
            const int grow = j0 + row;
            const int jl = jlist[grow < nact ? grow : 0];
            const float dsv = ds_all[jl];
            bf16x8 vp = *(const bf16x8*)(Vp_b + (size_t)jl*HF + bcol);
            f32x4 w0 = *(const f32x4*)&vw1l[bcol];
            f32x4 w1 = *(const f32x4*)&vw1l[bcol+4];
            bf16x8 pk;
            #pragma unroll
            for (int q = 0; q < 4; ++q) {
                pk[q]   = (short)f2bf(silu_f(bf2f(vp[q])   + dsv*w0[q]));
                pk[q+4] = (short)f2bf(silu_f(bf2f(vp[q+4]) + dsv*w1[q]));
            }
            *(bf16x8*)(smem + 8192 + row*256 + ((bcol*2) ^ ((row & 7) << 4))) = pk;
        }
        __syncthreads();   // bar 3: V + attn_e ready

        // ---- phase 4: v-GEMM + h accumulate (no barrier) ----
        bf16x8 vf[4];
        {
            int arow = wj*16 + lr;
            int rb = 8192 + arow*256, sw = (arow & 7) << 4;
            #pragma unroll
            for (int ks = 0; ks < 4; ++ks)
                vf[ks] = *(bf16x8*)(smem + rb + ((lg*16 + ks*64) ^ sw));
        }
        float ae[4];
        #pragma unroll
        for (int r = 0; r < 4; ++r) { ae[r] = attn_e[wj*16 + lg*4 + r]; sae += ae[r]; }
        #pragma unroll
        for (int nt = 0; nt < 4; ++nt) {
            f32x4 a = (f32x4){0.f,0.f,0.f,0.f};
            #pragma unroll
            for (int ks = 0; ks < 4; ++ks)
                a = __builtin_amdgcn_mfma_f32_16x16x32_bf16(vf[ks], wv[nt][ks], a, 0,0,0);
            hacc[nt] += ae[0]*a[0] + ae[1]*a[1] + ae[2]*a[2] + ae[3]*a[3];
        }
    }

    // ---- final reductions ----
    #pragma unroll
    for (int nt = 0; nt < 4; ++nt) {
        hacc[nt] += __shfl_xor(hacc[nt],16);
        hacc[nt] += __shfl_xor(hacc[nt],32);
    }
    sae += __shfl_xor(sae,16);
    sae += __shfl_xor(sae,32);
    if (lg == 0) {
        #pragma unroll
        for (int nt = 0; nt < 4; ++nt)
            hred[wj*128 + wn*64 + nt*16 + lr] = hacc[nt] + vb2v[nt]*sae;
    }
    xa0 += __shfl_xor(xa0,1);  xa1 += __shfl_xor(xa1,1);  xa2 += __shfl_xor(xa2,1);
    xa0 += __shfl_xor(xa0,2);  xa1 += __shfl_xor(xa1,2);  xa2 += __shfl_xor(xa2,2);
    xa0 += __shfl_xor(xa0,4);  xa1 += __shfl_xor(xa1,4);  xa2 += __shfl_xor(xa2,4);
    xa0 += __shfl_xor(xa0,8);  xa1 += __shfl_xor(xa1,8);  xa2 += __shfl_xor(xa2,8);
    xa0 += __shfl_xor(xa0,16); xa1 += __shfl_xor(xa1,16); xa2 += __shfl_xor(xa2,16);
    xa0 += __shfl_xor(xa0,32); xa1 += __shfl_xor(xa1,32); xa2 += __shfl_xor(xa2,32);
    if (lane == 0) { xw[w*3+0]=xa0; xw[w*3+1]=xa1; xw[w*3+2]=xa2; }
    __syncthreads();

    const float lm = ligand_mask[ii];
    if (t < HF) {
        float v = (hred[t] + hred[128+t]) * 0.01f * lm;
        atomicAdd(&out[(size_t)ii*HF + t], v);
    }
    if (t < 3) {
        float v = (xw[t] + xw[3+t] + xw[6+t] + xw[9+t]) * 0.01f * lm;
        atomicAdd(&out[(size_t)NB*NL*HF + ii*3 + t], v);
    }
}

extern "C" void kernel_launch(void* const* d_in, const int* in_sizes, int n_in,
                              void* d_out, int out_size, void* d_ws, size_t ws_size,
                              hipStream_t stream) {
    const float* h_ligand     = (const float*)d_in[0];
    const float* x_ligand     = (const float*)d_in[1];
    const float* h_protein    = (const float*)d_in[2];
    const float* x_protein    = (const float*)d_in[3];
    const float* ligand_mask  = (const float*)d_in[4];
    const float* protein_mask = (const float*)d_in[5];
    const float* aW1 = (const float*)d_in[6];
    const float* ab1 = (const float*)d_in[7];
    const float* aW2 = (const float*)d_in[8];
    const float* ab2 = (const float*)d_in[9];
    const float* aW3 = (const float*)d_in[10];
    const float* ab3 = (const float*)d_in[11];
    const float* vW1 = (const float*)d_in[12];
    const float* vb1 = (const float*)d_in[13];
    const float* vW2 = (const float*)d_in[14];
    const float* vb2 = (const float*)d_in[15];
    const float* cW1 = (const float*)d_in[16];
    const float* cb1 = (const float*)d_in[17];
    const float* cW2 = (const float*)d_in[18];
    const float* cb2 = (const float*)d_in[19];

    float* Al = (float*)d_ws;                              // 512*128 f32
    float* Cl = Al + 512*HF;                               // 512*128 f32
    unsigned short* Ap  = (unsigned short*)(Cl + 512*HF);  // 4096*128 bf16
    unsigned short* Vp  = Ap + (size_t)NB*NP*HF;
    unsigned short* Cp  = Vp + (size_t)NB*NP*HF;
    unsigned short* WaT = Cp + (size_t)NB*NP*HF;           // 128*128 bf16
    unsigned short* WvT = WaT + HF*HF;

    hipMemsetAsync(d_out, 0, (size_t)out_size*sizeof(float), stream);

    precompute_kernel<<<592, 128, 0, stream>>>(
        h_ligand, h_protein, aW1, ab1, vW1, vb1, cW1, cb1, aW2, vW2,
        Al, Cl, Ap, Vp, Cp, WaT, WvT);

    egnn_main_kernel<<<NB*NL*2, 256, 0, stream>>>(
        x_ligand, x_protein, ligand_mask, protein_mask,
        aW1, ab2, aW3, ab3, vW1, vb2, cW1, cW2, cb2,
        Al, Cl, Ap, Vp, Cp, WaT, WvT, (float*)d_out);
}